// Round 9
// baseline (447.254 us; speedup 1.0000x reference)
//
#include <hip/hip_runtime.h>
#include <hip/hip_bf16.h>

#define NN 20000
#define EE 640000
#define FIN 128
#define CT 8
#define LT 200000
#define HEADS 8
#define HDIM 64
#define F1 16
#define F2 512
#define OUTF 576

typedef short s16x8 __attribute__((ext_vector_type(8)));
typedef float f32x4 __attribute__((ext_vector_type(4)));

static __device__ __forceinline__ unsigned f2bf_bits(float x) {
  unsigned u = __float_as_uint(x);
  return (u + 0x7fffu + ((u >> 16) & 1u)) >> 16;
}

// async global->LDS, 16B per lane; LDS dest is wave-uniform base + lane*16
static __device__ __forceinline__ void gl16(const void* g, void* l) {
  __builtin_amdgcn_global_load_lds(
      (const __attribute__((address_space(1))) unsigned*)g,
      (__attribute__((address_space(3))) unsigned*)l, 16, 0, 0);
}

// ================= device bodies (blockIdx passed in for fusion) =================

// conv-weight transforms + att fold (124 blocks)
static __device__ void dev_prep_all(
    int b, int t, const float* __restrict__ cw1, float* __restrict__ wt1,
    const float* __restrict__ cw2, short* __restrict__ wb2,
    const float* __restrict__ cw3, short* __restrict__ wb3,
    const float* __restrict__ W2, const float* __restrict__ asrc,
    const float* __restrict__ adst, float* __restrict__ WS, float* __restrict__ WD) {
  if (b < 3) {
    int i = b * 256 + t;
    if (i < 32 * 8 * 3) {
      int o = i / 24, r = i % 24;
      int c = r / 3, k = r % 3;
      wt1[(c * 3 + k) * 32 + o] = cw1[i];
    }
  } else if (b < 27) {
    int i = (b - 3) * 256 + t;  // < 6144
    int o = i / 96, r = i % 96;
    int ic = r / 3, kk = r % 3;
    wb2[o * 96 + kk * 32 + ic] = (short)f2bf_bits(cw2[i]);
  } else if (b < 123) {
    int i = (b - 27) * 256 + t;  // < 24576
    int o = i / 192, r = i % 192;
    int ic = r / 3, kk = r % 3;
    wb3[o * 192 + kk * 64 + ic] = (short)f2bf_bits(cw3[i]);
  } else {
    int k = (t & 127) >> 3, h = t & 7;
    const float* av = (t < 128) ? asrc : adst;
    float acc = 0.f;
    for (int d = 0; d < 64; d++) acc += W2[k * F2 + h * 64 + d] * av[h * 64 + d];
    ((t < 128) ? WS : WD)[k * 8 + h] = acc;
  }
}

// conv1: register-tiled VALU conv, C=8 O=32 P=4 (3125 blocks)
static __device__ void dev_conv_fast(
    char* smp, int b, int t, const float* __restrict__ in,
    __hip_bfloat16* __restrict__ out, const float* __restrict__ wt,
    const float* __restrict__ bias) {
  constexpr int C = 8, O = 32, P = 4, OCG = O / 2;
  float (*tile)[68] = (float(*)[68])smp;                       // 2176 B
  __hip_bfloat16 (*ot)[66] = (__hip_bfloat16(*)[66])(smp + 2176);  // +4224 = 6400 B
  int ocg = t % OCG;
  int pg = t / OCG;
  long base = (long)b * 64;

  for (int i = t; i < C * 66; i += 256) {
    int c = i / 66, p = i % 66;
    long l = base + p - 1;
    tile[c][p] = (l >= 0 && l < LT) ? in[(long)c * LT + l] : 0.f;
  }
  __syncthreads();

  int oc0 = 2 * ocg;
  int p0 = pg * P;
  float acc[2][P];
#pragma unroll
  for (int j = 0; j < 2; j++)
#pragma unroll
    for (int p = 0; p < P; p++) acc[j][p] = 0.f;

  for (int ic = 0; ic < C; ic++) {
    float x[P + 2];
#pragma unroll
    for (int q = 0; q < P / 4; q++) {
      float4 v = *(const float4*)&tile[ic][p0 + 4 * q];
      x[4 * q] = v.x; x[4 * q + 1] = v.y; x[4 * q + 2] = v.z; x[4 * q + 3] = v.w;
    }
    {
      float2 v = *(const float2*)&tile[ic][p0 + P];
      x[P] = v.x; x[P + 1] = v.y;
    }
    const float* wrow = wt + (long)ic * 3 * O;
    float wv[3][2];
#pragma unroll
    for (int kk = 0; kk < 3; kk++) {
      float2 w2 = *(const float2*)&wrow[kk * O + oc0];
      wv[kk][0] = w2.x; wv[kk][1] = w2.y;
    }
#pragma unroll
    for (int kk = 0; kk < 3; kk++)
#pragma unroll
      for (int j = 0; j < 2; j++)
#pragma unroll
        for (int p = 0; p < P; p++) acc[j][p] += x[p + kk] * wv[kk][j];
  }
  float b0 = bias[oc0], b1 = bias[oc0 + 1];
#pragma unroll
  for (int p = 0; p < P; p++) {
    ot[oc0][p0 + p] = __float2bfloat16(fmaxf(acc[0][p] + b0, 0.f));
    ot[oc0 + 1][p0 + p] = __float2bfloat16(fmaxf(acc[1][p] + b1, 0.f));
  }
  __syncthreads();
  for (int i = t; i < O * 32; i += 256) {
    int oc = i >> 5, pp = i & 31;
    unsigned v = ((const unsigned*)&ot[oc][0])[pp];
    *(unsigned*)&out[(long)oc * LT + base + 2 * pp] = v;
  }
}

// MFMA conv1d(k=3, SAME): block = 128 positions x O channels; u32 staging.
// v3: output repack+flush in TWO channel-halves -> LDS = max(SH_X, half SH_O)
// (was full SH_O = 33792B for O=128, capping L4 at 4 blocks/CU = 39% occ).
template <int C, int O, int MPW>
static __device__ void dev_conv_mfma(
    char* smp, int b, int t, const short* __restrict__ in,
    short* __restrict__ out, const short* __restrict__ w,
    const float* __restrict__ bias) {
  constexpr int K = 3 * C;
  constexpr int NS = K / 32;
  constexpr int XP = C + 8;
  constexpr int OP = 132;
  short* xT = (short*)smp;
  long base = (long)b * 128;

  if (base >= 2 && base + 131 < LT) {
    for (int idx = t; idx < C * 67; idx += 256) {
      int ic = idx / 67, q = idx % 67;
      unsigned v = *(const unsigned*)(in + (long)ic * LT + base + 2 * q - 2);
      int p0 = 2 * q - 1;
      if (q > 0) xT[p0 * XP + ic] = (short)(v & 0xffffu);
      if (q < 66) xT[(p0 + 1) * XP + ic] = (short)(v >> 16);
    }
  } else {
    for (int idx = t; idx < C * 132; idx += 256) {
      int ic = idx / 132, p = idx % 132;
      long l = base + p - 1;
      xT[p * XP + ic] = (l >= 0 && l < LT) ? in[(long)ic * LT + l] : (short)0;
    }
  }
  __syncthreads();

  int wave = t >> 6, lane = t & 63;
  int n = lane & 15, kg = lane >> 4;
  int m0 = wave * (MPW * 16);

  f32x4 acc[MPW][8] = {};
#pragma unroll
  for (int s = 0; s < NS; s++) {
    const int kk = (s * 32) / C;
    const int ic0 = (s * 32) % C + kg * 8;
    s16x8 a[MPW];
#pragma unroll
    for (int mi = 0; mi < MPW; mi++)
      a[mi] = *(const s16x8*)(w + (long)(m0 + mi * 16 + n) * K + s * 32 + kg * 8);
#pragma unroll
    for (int nt = 0; nt < 8; nt++) {
      s16x8 bb = *(const s16x8*)(xT + (nt * 16 + n + kk) * XP + ic0);
#pragma unroll
      for (int mi = 0; mi < MPW; mi++)
        acc[mi][nt] = __builtin_amdgcn_mfma_f32_16x16x32_bf16(a[mi], bb, acc[mi][nt], 0, 0, 0);
    }
  }

  __syncthreads();
  short* ob = (short*)smp;
  const unsigned* obu = (const unsigned*)smp;
#pragma unroll
  for (int half = 0; half < 2; half++) {
    const int olo = half * (O / 2);
#pragma unroll
    for (int mi = 0; mi < MPW; mi++) {
      int obase = m0 + mi * 16;
      if (obase >= olo && obase < olo + O / 2) {
        int o = obase + kg * 4;
#pragma unroll
        for (int nt = 0; nt < 8; nt++) {
          int p = nt * 16 + n;
#pragma unroll
          for (int r = 0; r < 4; r++) {
            float v = fmaxf(acc[mi][nt][r] + bias[o + r], 0.f);
            ob[(o - olo + r) * OP + p] = (short)f2bf_bits(v);
          }
        }
      }
    }
    __syncthreads();
    for (int idx = t; idx < (O / 2) * 64; idx += 256) {
      int o = idx >> 6, q = idx & 63;
      long l = base + 2 * q;
      if (l < LT)
        *(unsigned*)(out + (long)(olo + o) * LT + l) = obu[o * (OP / 2) + q];
    }
    __syncthreads();
  }
}

// 256-thread scan over NN with fused dinv (1 block)
static __device__ void dev_scan(
    char* smp, int t, const int* __restrict__ deg, int* __restrict__ offs,
    float* __restrict__ dinv) {
  int* sums = (int*)smp;
  const int CH = 79;  // 256*79 = 20224 >= NN
  int base = t * CH;
  int s = 0;
  for (int i = 0; i < CH; i++) {
    int idx = base + i;
    if (idx < NN) s += deg[idx] + 1;
  }
  sums[t] = s;
  __syncthreads();
  for (int off = 1; off < 256; off <<= 1) {
    int v = (t >= off) ? sums[t - off] : 0;
    __syncthreads();
    sums[t] += v;
    __syncthreads();
  }
  int run = (t > 0) ? sums[t - 1] : 0;
  for (int i = 0; i < CH; i++) {
    int idx = base + i;
    if (idx < NN) {
      int d = deg[idx];
      offs[idx] = run;
      dinv[idx] = rsqrtf((float)(d + 1));
      run += d + 1;
    }
  }
  if (t == 255) offs[NN] = sums[255];
}

static __device__ void dev_fill(
    int b, int t, const int* __restrict__ src, const int* __restrict__ dst,
    const int* __restrict__ offs, int* __restrict__ cursor, int* __restrict__ csr) {
  int e = b * 256 + t;
  if (e < EE) {
    int d = dst[e];
    int pos = atomicAdd(&cursor[d], 1);
    csr[offs[d] + pos] = src[e];
  } else if (e < EE + NN) {
    int i = e - EE;
    int pos = atomicAdd(&cursor[i], 1);
    csr[offs[i] + pos] = i;
  }
}

// h1: LDS-tiled skinny GEMM, dinv folded (1250 blocks)
static __device__ void dev_h1(
    char* smp, int b, int t, const float* __restrict__ x,
    const float* __restrict__ W1, const float* __restrict__ dinv,
    float* __restrict__ h1s) {
  float* ws = (float*)smp;             // 8192 B
  float* xs = (float*)(smp + 8192);    // 16*132*4 = 8448 B
  int i0 = b * 16;
  for (int i = t; i < 512; i += 256)
    *(float4*)&ws[4 * i] = *(const float4*)&W1[4 * i];
  for (int i = t; i < 512; i += 256) {
    int nl = i >> 5, q = i & 31;
    *(float4*)&xs[nl * 132 + 4 * q] = *(const float4*)&x[(long)(i0 + nl) * FIN + 4 * q];
  }
  __syncthreads();
  int nl = t >> 4, f = t & 15;
  float acc = 0.f;
#pragma unroll 8
  for (int k = 0; k < FIN; k++) acc += xs[nl * 132 + k] * ws[k * 16 + f];
  int n = i0 + nl;
  h1s[n * F1 + f] = acc * dinv[n];
}

// fw1->bf16 + fw2 transpose (1344 blocks)
static __device__ void dev_fwprep(
    int b, int t, const float* __restrict__ fw1, __hip_bfloat16* __restrict__ w1b,
    const float* __restrict__ fw2, float* __restrict__ fw2t) {
  if (b < 1280) {
    int i = b * 256 + t;
    w1b[i] = __float2bfloat16(fw1[i]);
  } else {
    int i = (b - 1280) * 256 + t;  // < 16384
    int o = i / 256, j = i % 256;
    fw2t[j * 64 + o] = fw2[i];
  }
}

// fc1 (m97-style LDS GEMM), 314 blocks
static __device__ void dev_fc1(
    char* smp, int bid, int t, const __hip_bfloat16* __restrict__ t3,
    const __hip_bfloat16* __restrict__ w, const float* __restrict__ fb1,
    float* __restrict__ out) {
  short* As = (short*)smp;             // [2][4096] shorts = 16 KB
  short* Bs = (short*)(smp + 16384);   // [2][4096] shorts = 16 KB
  int wid = t >> 6, lane = t & 63;
  int bn = bid & 1, bm = bid >> 1;
  int mrow = lane & 15, kg = lane >> 4;

  const char* tb = (const char*)t3;
  const char* wb = (const char*)w;
  int u0 = wid * 128 + lane;
  int u1 = u0 + 64;
  int ra0 = u0 >> 2, ca0 = u0 & 3;
  int ra1 = u1 >> 2, ca1 = u1 & 3;
  long ga0 = ((long)min(bm * 128 + ra0, NN - 1) * 1280 + ca0 * 8) * 2;
  long ga1 = ((long)min(bm * 128 + ra1, NN - 1) * 1280 + ca1 * 8) * 2;
  long gb0 = ((long)(bn * 128 + ra0) * 1280 + ca0 * 8) * 2;
  long gb1 = ((long)(bn * 128 + ra1) * 1280 + ca1 * 8) * 2;
  int l0 = (wid * 2 + 0) * 512;
  int l1 = (wid * 2 + 1) * 512;

  auto stage = [&](int buf, int k0) {
    long kb = (long)k0 * 2;
    gl16(tb + ga0 + kb, As + buf * 4096 + l0);
    gl16(tb + ga1 + kb, As + buf * 4096 + l1);
    gl16(wb + gb0 + kb, Bs + buf * 4096 + l0);
    gl16(wb + gb1 + kb, Bs + buf * 4096 + l1);
  };

  stage(0, 0);
  __syncthreads();

  int wr = wid >> 1, wc = wid & 1;
  f32x4 acc[4][4] = {};
  for (int s = 0; s < 40; s++) {
    int buf = s & 1;
    if (s + 1 < 40) stage(buf ^ 1, (s + 1) * 32);
    s16x8 a[4], bb[4];
#pragma unroll
    for (int mi = 0; mi < 4; mi++)
      a[mi] = *(const s16x8*)&As[buf * 4096 + (wr * 64 + mi * 16 + mrow) * 32 + kg * 8];
#pragma unroll
    for (int ni = 0; ni < 4; ni++)
      bb[ni] = *(const s16x8*)&Bs[buf * 4096 + (wc * 64 + ni * 16 + mrow) * 32 + kg * 8];
#pragma unroll
    for (int mi = 0; mi < 4; mi++)
#pragma unroll
      for (int ni = 0; ni < 4; ni++)
        acc[mi][ni] = __builtin_amdgcn_mfma_f32_16x16x32_bf16(a[mi], bb[ni], acc[mi][ni], 0, 0, 0);
    __syncthreads();
  }

  int node_base = bm * 128 + wr * 64 + kg * 4;
  int col_base = bn * 128 + wc * 64 + mrow;
#pragma unroll
  for (int ni = 0; ni < 4; ni++) {
    int col = col_base + ni * 16;
    float bias = fb1[col];
#pragma unroll
    for (int mi = 0; mi < 4; mi++) {
      int node = node_base + mi * 16;
#pragma unroll
      for (int r = 0; r < 4; r++) {
        if (node + r < NN)
          out[(long)(node + r) * 256 + col] = fmaxf(acc[mi][ni][r] + bias, 0.f);
      }
    }
  }
}

// gcn: pre-scaled h1s, 4 waves/block (5000 blocks)
static __device__ void dev_gcn(
    int b, int t, const float* __restrict__ h1s, const int* __restrict__ offs,
    const int* __restrict__ csr, const float* __restrict__ dinv,
    const float* __restrict__ b1, float* __restrict__ g) {
  int wave = t >> 6;
  int lane = t & 63;
  int i = b * 4 + wave;
  int f = lane & 15, grp = lane >> 4;
  int beg = offs[i], end = offs[i + 1];
  float acc = 0.f;
  for (int idx = beg + grp; idx < end; idx += 4)
    acc += h1s[csr[idx] * F1 + f];
  acc += __shfl_down(acc, 32);
  acc += __shfl_down(acc, 16);
  if (lane < 16) g[i * F1 + f] = fmaxf(acc * dinv[i] + b1[f], 0.f);
}

// fc2 v2: block = 16 nodes (LDS 16640B, was 33792 -> doubles blocks/CU).
// wave = 4 nodes x 64 outputs.
static __device__ void dev_fc2(
    char* smp, int b, int t, const float* __restrict__ fc1o,
    const float* __restrict__ fw2t, const float* __restrict__ fb2,
    float* __restrict__ out) {
  float* sh = (float*)smp;  // 16*260 floats = 16640 B
  int m0 = b * 16;
  for (int i = t; i < 1024; i += 256) {
    int nd = i >> 6, q = i & 63;
    *(float4*)&sh[nd * 260 + 4 * q] = *(const float4*)&fc1o[(long)(m0 + nd) * 256 + 4 * q];
  }
  __syncthreads();
  int wave = t >> 6, o = t & 63;
  int nb = wave * 4;
  float acc[4];
  float bias = fb2[o];
#pragma unroll
  for (int i = 0; i < 4; i++) acc[i] = bias;
  for (int j = 0; j < 256; j++) {
    float wv = fw2t[j * 64 + o];
#pragma unroll
    for (int i = 0; i < 4; i++) acc[i] += sh[(nb + i) * 260 + j] * wv;
  }
#pragma unroll
  for (int i = 0; i < 4; i++)
    out[(long)(m0 + nb + i) * OUTF + F2 + o] = acc[i];
}

// h2att: block = 32 nodes (625 blocks)
static __device__ void dev_h2att(
    char* smp, int b, int t, const float* __restrict__ g,
    const float* __restrict__ W2, const float* __restrict__ WS,
    const float* __restrict__ WD, unsigned* __restrict__ h2hm,
    float* __restrict__ AS, float* __restrict__ AD) {
  float* glb = (float*)smp;  // 32*20 floats
  int i0 = b * 32;
  for (int idx = t; idx < 512; idx += 256)
    glb[(idx >> 4) * 20 + (idx & 15)] = g[i0 * 16 + idx];
  __syncthreads();

  int f0 = 2 * t;
  int h = t >> 5, c32 = t & 31;
  float w0[16], w1[16];
#pragma unroll
  for (int k = 0; k < 16; k++) {
    float2 wv = *(const float2*)&W2[k * F2 + f0];
    w0[k] = wv.x; w1[k] = wv.y;
  }
  for (int nl = 0; nl < 32; nl++) {
    float a0 = 0.f, a1 = 0.f;
#pragma unroll
    for (int kk = 0; kk < 4; kk++) {
      f32x4 gv = *(const f32x4*)&glb[nl * 20 + 4 * kk];
#pragma unroll
      for (int r = 0; r < 4; r++) {
        a0 += gv[r] * w0[4 * kk + r];
        a1 += gv[r] * w1[4 * kk + r];
      }
    }
    h2hm[((long)h * NN + i0 + nl) * 32 + c32] = f2bf_bits(a0) | (f2bf_bits(a1) << 16);
  }
  int nl = t >> 3, hh = t & 7;
  float s = 0.f, d = 0.f;
#pragma unroll
  for (int k = 0; k < 16; k++) {
    float gv = glb[nl * 20 + k];
    s += gv * WS[k * 8 + hh];
    d += gv * WD[k * 8 + hh];
  }
  AS[(long)hh * NN + i0 + nl] = s;
  AD[(long)hh * NN + i0 + nl] = d;
}

// ================= fused launches =================

// L1: prep (124) + zero CURSOR..DEG (157) = 281 blocks
__global__ __launch_bounds__(256) void k_prep(
    const float* cw1, float* wt1, const float* cw2, short* wb2,
    const float* cw3, short* wb3, const float* W2, const float* asrc,
    const float* adst, float* WS, float* WD, int* zbase) {
  int b = blockIdx.x, t = threadIdx.x;
  if (b < 124) dev_prep_all(b, t, cw1, wt1, cw2, wb2, cw3, wb3, W2, asrc, adst, WS, WD);
  else {
    int i = (b - 124) * 256 + t;
    if (i < 40000) zbase[i] = 0;
  }
}

// L2: conv1 (3125) + deg (2500) = 5625 blocks, 6400 B dyn LDS
__global__ __launch_bounds__(256) void k_conv1_deg(
    const float* temporal, __hip_bfloat16* T1b, const float* wt1, const float* cb1,
    const int* e_dst, int* deg) {
  extern __shared__ char smem[];
  int b = blockIdx.x;
  if (b < 3125) dev_conv_fast(smem, b, threadIdx.x, temporal, T1b, wt1, cb1);
  else {
    int e = (b - 3125) * 256 + threadIdx.x;
    if (e < EE) atomicAdd(&deg[e_dst[e]], 1);
  }
}

// L3: conv2 (1563) + scan (1) = 1564 blocks, 10560 B dyn LDS
__global__ __launch_bounds__(256) void k_conv2_scan(
    const short* T1b, short* T2b, const short* wb2, const float* cb2,
    const int* deg, int* offs, float* dinv) {
  extern __shared__ char smem[];
  int b = blockIdx.x;
  if (b < 1563) dev_conv_mfma<32, 64, 1>(smem, b, threadIdx.x, T1b, T2b, wb2, cb2);
  else dev_scan(smem, threadIdx.x, deg, offs, dinv);
}

// L4: conv3 (1563) + fill (2579) + h1 (1250) + fwprep (1344) = 6736, 19008 B
__global__ __launch_bounds__(256) void k_conv3_misc(
    const short* T2b, short* T3b, const short* wb3, const float* cb3,
    const int* e_src, const int* e_dst, const int* offs, int* cursor, int* csr,
    const float* x, const float* W1, const float* dinv, float* h1s,
    const float* fw1, __hip_bfloat16* w1b, const float* fw2, float* fw2t) {
  extern __shared__ char smem[];
  int b = blockIdx.x, t = threadIdx.x;
  if (b < 1563) dev_conv_mfma<64, 128, 2>(smem, b, t, T2b, T3b, wb3, cb3);
  else if (b < 4142) dev_fill(b - 1563, t, e_src, e_dst, offs, cursor, csr);
  else if (b < 5392) dev_h1(smem, b - 4142, t, x, W1, dinv, h1s);
  else dev_fwprep(b - 5392, t, fw1, w1b, fw2, fw2t);
}

// L5: fc1 (314) + gcn (5000) = 5314 blocks, 32768 B dyn LDS
__global__ __launch_bounds__(256) void k_fc1_gcn(
    const __hip_bfloat16* t3, const __hip_bfloat16* w, const float* fb1, float* fc1o,
    const float* h1s, const int* offs, const int* csr, const float* dinv,
    const float* b1, float* g) {
  extern __shared__ char smem[];
  int b = blockIdx.x, t = threadIdx.x;
  if (b < 314) dev_fc1(smem, b, t, t3, w, fb1, fc1o);
  else dev_gcn(b - 314, t, h1s, offs, csr, dinv, b1, g);
}

// L6: fc2 (1250) + h2att (625) = 1875 blocks, 16640 B dyn LDS
__global__ __launch_bounds__(256) void k_fc2_h2att(
    const float* fc1o, const float* fw2t, const float* fb2, float* out,
    const float* g, const float* W2, const float* WS, const float* WD,
    unsigned* h2hm, float* AS, float* AD) {
  extern __shared__ char smem[];
  int b = blockIdx.x, t = threadIdx.x;
  if (b < 1250) dev_fc2(smem, b, t, fc1o, fw2t, fb2, out);
  else dev_h2att(smem, b - 1250, t, g, W2, WS, WD, h2hm, AS, AD);
}

// L7: gat v3 (known-good 68us): one wave per (dst node, head).
__global__ __launch_bounds__(256) void gat_fused_kernel(
    const unsigned* __restrict__ h2hm, const float* __restrict__ AS,
    const float* __restrict__ AD, const int* __restrict__ offs,
    const int* __restrict__ csr, const float* __restrict__ b2,
    float* __restrict__ out) {
  __shared__ __align__(16) unsigned long long pairs[4][64];
  __shared__ __align__(16) float accb[4][8][68];
  int h = blockIdx.x & 7;
  int gn = blockIdx.x >> 3;
  int wave = threadIdx.x >> 6;
  int lane = threadIdx.x & 63;
  int i = gn * 4 + wave;
  int beg = offs[i], end = offs[i + 1];
  const float* ASh = AS + (long)h * NN;
  float ad = AD[(long)h * NN + i];
  const char* hb2 = (const char*)(h2hm + (long)h * NN * 32);
  int octet = lane >> 3, q = lane & 7;
  unsigned laneoff = (unsigned)q * 16u;
  unsigned long long* prs = &pairs[wave][0];

  float acc[8] = {0.f, 0.f, 0.f, 0.f, 0.f, 0.f, 0.f, 0.f};
  float sum = 0.f;

  for (int c = beg; c < end; c += 64) {
    int cnt = end - c;
    if (cnt > 64) cnt = 64;
    unsigned off = 0u;
    float ex = 0.f;
    if (lane < cnt) {
      int s = csr[c + lane];
      float e = ASh[s] + ad;
      e = (e >= 0.f) ? e : 0.2f * e;
      ex = __expf(e);
      sum += ex;
      off = (unsigned)s << 7;  // s * 128 bytes
    }
    asm volatile("" ::: "memory");
    prs[lane] = ((unsigned long long)__float_as_uint(ex) << 32) | off;
    asm volatile("" ::: "memory");
    int nj = (cnt + 7) >> 3;
    const unsigned long long* pp = prs + octet;
#pragma unroll 2
    for (int j = 0; j < nj; j++) {
      unsigned long long pr = pp[(long)j * 8];
      unsigned voff = (unsigned)pr | laneoff;
      float aj = __uint_as_float((unsigned)(pr >> 32));
      uint4 v = *(const uint4*)(hb2 + voff);
      acc[0] += __uint_as_float(v.x << 16) * aj;
      acc[1] += __uint_as_float(v.x & 0xffff0000u) * aj;
      acc[2] += __uint_as_float(v.y << 16) * aj;
      acc[3] += __uint_as_float(v.y & 0xffff0000u) * aj;
      acc[4] += __uint_as_float(v.z << 16) * aj;
      acc[5] += __uint_as_float(v.z & 0xffff0000u) * aj;
      acc[6] += __uint_as_float(v.w << 16) * aj;
      acc[7] += __uint_as_float(v.w & 0xffff0000u) * aj;
    }
    asm volatile("" ::: "memory");
  }
#pragma unroll
  for (int o = 32; o > 0; o >>= 1) sum += __shfl_xor(sum, o, 64);
  float rinv = 1.f / (sum + 1e-16f);
  float* ab = &accb[wave][octet][q * 8];
  f32x4 lo = {acc[0], acc[1], acc[2], acc[3]};
  f32x4 hi = {acc[4], acc[5], acc[6], acc[7]};
  *(f32x4*)ab = lo;
  *(f32x4*)(ab + 4) = hi;
  asm volatile("" ::: "memory");
  float r = 0.f;
#pragma unroll
  for (int o = 0; o < 8; o++) r += accb[wave][o][lane];
  out[(long)i * OUTF + h * 64 + lane] = r * rinv + b2[h * 64 + lane];
}

// ---------------- launcher ----------------

extern "C" void kernel_launch(void* const* d_in, const int* in_sizes, int n_in,
                              void* d_out, int out_size, void* d_ws, size_t ws_size,
                              hipStream_t stream) {
  const float* x        = (const float*)d_in[0];
  const int*   eidx     = (const int*)d_in[1];
  const float* temporal = (const float*)d_in[2];
  const float* W1       = (const float*)d_in[3];
  const float* b1       = (const float*)d_in[4];
  const float* W2       = (const float*)d_in[5];
  const float* att_src  = (const float*)d_in[6];
  const float* att_dst  = (const float*)d_in[7];
  const float* b2       = (const float*)d_in[8];
  const float* cw1      = (const float*)d_in[9];
  const float* cb1      = (const float*)d_in[10];
  const float* cw2      = (const float*)d_in[11];
  const float* cb2      = (const float*)d_in[12];
  const float* cw3      = (const float*)d_in[13];
  const float* cb3      = (const float*)d_in[14];
  const float* fw1      = (const float*)d_in[15];
  const float* fb1      = (const float*)d_in[16];
  const float* fw2      = (const float*)d_in[17];
  const float* fb2      = (const float*)d_in[18];
  float* out = (float*)d_out;

  const int* e_src = eidx;
  const int* e_dst = eidx + EE;

  char* ws = (char*)d_ws;
  // ---- workspace layout with lifetime-disjoint aliasing (launch index L1..L7) ----
  int*   CURSOR = (int*)  (ws + 0);          // [L1 zero, L4 fill]      80,000
  int*   DEG    = (int*)  (ws + 80000);      // [L1 zero, L2 W, L3 R]   -> 160,000
  int*   OFFS   = (int*)  (ws + 160000);     // [L3 W, L4/L5/L7 R]      -> 240,128
  float* DINV   = (float*)(ws + 240128);     // [L3 W, L4/L5 R]         -> 320,128
  int*   CSR    = (int*)  (ws + 320128);     // [L4 W, L5/L7 R]         -> 2,960,128
  float* H1S    = (float*)(ws + 2960128);    // [L4 W, L5 R]            -> 4,240,128
  float* G      = (float*)(ws + 4240128);    // [L5 W, L6 R]            -> 5,520,128
  float* AS     = (float*)(ws + 5520128);    // [L6 W, L7 R]            -> 6,160,128
  float* AD     = (float*)(ws + 6160128);    // [L6 W, L7 R]            -> 6,800,128
  // big buffers, time-disjoint aliases:
  __hip_bfloat16* T2b = (__hip_bfloat16*)(ws + 6800128);   // [L3 W, L4 R] 25.6M -> 32,400,128
  float* FC1OUT = (float*)(ws + 6800128);                  // [L5 W, L6 R] 20.48M (T2b dead)
  __hip_bfloat16* T1b = (__hip_bfloat16*)(ws + 32400128);  // [L2 W, L3 R] 12.8M -> 45,200,128
  unsigned* H2HM = (unsigned*)(ws + 32400128);             // [L6 W, L7 R] 20.48M (T3b dead)
  __hip_bfloat16* T3b = (__hip_bfloat16*)(ws + 32400128);  // [L4 W, L5 R] 51.2M -> 83,600,128 (T1b dead)
  __hip_bfloat16* FW1BF = (__hip_bfloat16*)(ws + 83600128);// [L4 W, L5 R] -> 84,255,488
  float* FW2T = (float*)(ws + 84255488);                   // [L4 W, L6 R] -> 84,321,024
  // conv weight + att-fold scratch in d_out (consumed before overwritten):
  float* WT1 = out;                              // [L1 W, L2 R] bytes 0..3,072
  short* WB2 = (short*)((char*)d_out + 3072);    // [L1 W, L3 R] -> 15,360
  short* WB3 = (short*)((char*)d_out + 15360);   // [L1 W, L4 R] -> 64,512
  float* WSM = (float*)((char*)d_out + 64512);   // [L1 W, L6 R] -> 65,024
  float* WDM = (float*)((char*)d_out + 65024);   // -> 65,536

  // L1: prep + zero(CURSOR,DEG = 40000 ints)
  k_prep<<<281, 256, 0, stream>>>(cw1, WT1, cw2, WB2, cw3, WB3,
                                  W2, att_src, att_dst, WSM, WDM, (int*)ws);
  // L2: conv1 || deg
  k_conv1_deg<<<5625, 256, 6400, stream>>>(temporal, T1b, WT1, cb1, e_dst, DEG);
  // L3: conv2 || scan(+dinv)
  k_conv2_scan<<<1564, 256, 10560, stream>>>((const short*)T1b, (short*)T2b, WB2, cb2,
                                             DEG, OFFS, DINV);
  // L4: conv3 || fill || h1 || fwprep
  k_conv3_misc<<<6736, 256, 19008, stream>>>((const short*)T2b, (short*)T3b, WB3, cb3,
                                             e_src, e_dst, OFFS, CURSOR, CSR,
                                             x, W1, DINV, H1S,
                                             fw1, FW1BF, fw2, FW2T);
  // L5: fc1 || gcn
  k_fc1_gcn<<<5314, 256, 32768, stream>>>(T3b, FW1BF, fb1, FC1OUT,
                                          H1S, OFFS, CSR, DINV, b1, G);
  // L6: fc2 || h2att
  k_fc2_h2att<<<1875, 256, 16640, stream>>>(FC1OUT, FW2T, fb2, out,
                                            G, W2, WSM, WDM, H2HM, AS, AD);
  // L7: gat
  gat_fused_kernel<<<(NN / 4) * 8, 256, 0, stream>>>(H2HM, AS, AD, OFFS, CSR, b2, out);
}

// Round 10
// 425.220 us; speedup vs baseline: 1.0518x; 1.0518x over previous
//
#include <hip/hip_runtime.h>
#include <hip/hip_bf16.h>

#define NN 20000
#define EE 640000
#define FIN 128
#define CT 8
#define LT 200000
#define HEADS 8
#define HDIM 64
#define F1 16
#define F2 512
#define OUTF 576

typedef short s16x8 __attribute__((ext_vector_type(8)));
typedef float f32x4 __attribute__((ext_vector_type(4)));

static __device__ __forceinline__ unsigned f2bf_bits(float x) {
  unsigned u = __float_as_uint(x);
  return (u + 0x7fffu + ((u >> 16) & 1u)) >> 16;
}

// async global->LDS, 16B per lane; LDS dest is wave-uniform base + lane*16
static __device__ __forceinline__ void gl16(const void* g, void* l) {
  __builtin_amdgcn_global_load_lds(
      (const __attribute__((address_space(1))) unsigned*)g,
      (__attribute__((address_space(3))) unsigned*)l, 16, 0, 0);
}

// ================= device bodies (blockIdx passed in for fusion) =================

// conv-weight transforms + att fold (124 blocks)
static __device__ void dev_prep_all(
    int b, int t, const float* __restrict__ cw1, float* __restrict__ wt1,
    const float* __restrict__ cw2, short* __restrict__ wb2,
    const float* __restrict__ cw3, short* __restrict__ wb3,
    const float* __restrict__ W2, const float* __restrict__ asrc,
    const float* __restrict__ adst, float* __restrict__ WS, float* __restrict__ WD) {
  if (b < 3) {
    int i = b * 256 + t;
    if (i < 32 * 8 * 3) {
      int o = i / 24, r = i % 24;
      int c = r / 3, k = r % 3;
      wt1[(c * 3 + k) * 32 + o] = cw1[i];
    }
  } else if (b < 27) {
    int i = (b - 3) * 256 + t;  // < 6144
    int o = i / 96, r = i % 96;
    int ic = r / 3, kk = r % 3;
    wb2[o * 96 + kk * 32 + ic] = (short)f2bf_bits(cw2[i]);
  } else if (b < 123) {
    int i = (b - 27) * 256 + t;  // < 24576
    int o = i / 192, r = i % 192;
    int ic = r / 3, kk = r % 3;
    wb3[o * 192 + kk * 64 + ic] = (short)f2bf_bits(cw3[i]);
  } else {
    int k = (t & 127) >> 3, h = t & 7;
    const float* av = (t < 128) ? asrc : adst;
    float acc = 0.f;
    for (int d = 0; d < 64; d++) acc += W2[k * F2 + h * 64 + d] * av[h * 64 + d];
    ((t < 128) ? WS : WD)[k * 8 + h] = acc;
  }
}

// conv1: register-tiled VALU conv, C=8 O=32 P=4 (3125 blocks)
static __device__ void dev_conv_fast(
    char* smp, int b, int t, const float* __restrict__ in,
    __hip_bfloat16* __restrict__ out, const float* __restrict__ wt,
    const float* __restrict__ bias) {
  constexpr int C = 8, O = 32, P = 4, OCG = O / 2;
  float (*tile)[68] = (float(*)[68])smp;                       // 2176 B
  __hip_bfloat16 (*ot)[66] = (__hip_bfloat16(*)[66])(smp + 2176);  // +4224 = 6400 B
  int ocg = t % OCG;
  int pg = t / OCG;
  long base = (long)b * 64;

  for (int i = t; i < C * 66; i += 256) {
    int c = i / 66, p = i % 66;
    long l = base + p - 1;
    tile[c][p] = (l >= 0 && l < LT) ? in[(long)c * LT + l] : 0.f;
  }
  __syncthreads();

  int oc0 = 2 * ocg;
  int p0 = pg * P;
  float acc[2][P];
#pragma unroll
  for (int j = 0; j < 2; j++)
#pragma unroll
    for (int p = 0; p < P; p++) acc[j][p] = 0.f;

  for (int ic = 0; ic < C; ic++) {
    float x[P + 2];
#pragma unroll
    for (int q = 0; q < P / 4; q++) {
      float4 v = *(const float4*)&tile[ic][p0 + 4 * q];
      x[4 * q] = v.x; x[4 * q + 1] = v.y; x[4 * q + 2] = v.z; x[4 * q + 3] = v.w;
    }
    {
      float2 v = *(const float2*)&tile[ic][p0 + P];
      x[P] = v.x; x[P + 1] = v.y;
    }
    const float* wrow = wt + (long)ic * 3 * O;
    float wv[3][2];
#pragma unroll
    for (int kk = 0; kk < 3; kk++) {
      float2 w2 = *(const float2*)&wrow[kk * O + oc0];
      wv[kk][0] = w2.x; wv[kk][1] = w2.y;
    }
#pragma unroll
    for (int kk = 0; kk < 3; kk++)
#pragma unroll
      for (int j = 0; j < 2; j++)
#pragma unroll
        for (int p = 0; p < P; p++) acc[j][p] += x[p + kk] * wv[kk][j];
  }
  float b0 = bias[oc0], b1 = bias[oc0 + 1];
#pragma unroll
  for (int p = 0; p < P; p++) {
    ot[oc0][p0 + p] = __float2bfloat16(fmaxf(acc[0][p] + b0, 0.f));
    ot[oc0 + 1][p0 + p] = __float2bfloat16(fmaxf(acc[1][p] + b1, 0.f));
  }
  __syncthreads();
  for (int i = t; i < O * 32; i += 256) {
    int oc = i >> 5, pp = i & 31;
    unsigned v = ((const unsigned*)&ot[oc][0])[pp];
    *(unsigned*)&out[(long)oc * LT + base + 2 * pp] = v;
  }
}

// MFMA conv1d(k=3, SAME): block = 128 positions x O channels; u32 staging.
// (round-8 single-flush body: VGPR 56. Round-9's two-half flush stretched
// acc live ranges across the half-0 flush -> VGPR 92, occupancy 39->20%,
// +17us. Reverted.)
template <int C, int O, int MPW>
static __device__ void dev_conv_mfma(
    char* smp, int b, int t, const short* __restrict__ in,
    short* __restrict__ out, const short* __restrict__ w,
    const float* __restrict__ bias) {
  constexpr int K = 3 * C;
  constexpr int NS = K / 32;
  constexpr int XP = C + 8;
  constexpr int OP = 132;
  short* xT = (short*)smp;
  long base = (long)b * 128;

  if (base >= 2 && base + 131 < LT) {
    for (int idx = t; idx < C * 67; idx += 256) {
      int ic = idx / 67, q = idx % 67;
      unsigned v = *(const unsigned*)(in + (long)ic * LT + base + 2 * q - 2);
      int p0 = 2 * q - 1;
      if (q > 0) xT[p0 * XP + ic] = (short)(v & 0xffffu);
      if (q < 66) xT[(p0 + 1) * XP + ic] = (short)(v >> 16);
    }
  } else {
    for (int idx = t; idx < C * 132; idx += 256) {
      int ic = idx / 132, p = idx % 132;
      long l = base + p - 1;
      xT[p * XP + ic] = (l >= 0 && l < LT) ? in[(long)ic * LT + l] : (short)0;
    }
  }
  __syncthreads();

  int wave = t >> 6, lane = t & 63;
  int n = lane & 15, kg = lane >> 4;
  int m0 = wave * (MPW * 16);

  f32x4 acc[MPW][8] = {};
#pragma unroll
  for (int s = 0; s < NS; s++) {
    const int kk = (s * 32) / C;
    const int ic0 = (s * 32) % C + kg * 8;
    s16x8 a[MPW];
#pragma unroll
    for (int mi = 0; mi < MPW; mi++)
      a[mi] = *(const s16x8*)(w + (long)(m0 + mi * 16 + n) * K + s * 32 + kg * 8);
#pragma unroll
    for (int nt = 0; nt < 8; nt++) {
      s16x8 bb = *(const s16x8*)(xT + (nt * 16 + n + kk) * XP + ic0);
#pragma unroll
      for (int mi = 0; mi < MPW; mi++)
        acc[mi][nt] = __builtin_amdgcn_mfma_f32_16x16x32_bf16(a[mi], bb, acc[mi][nt], 0, 0, 0);
    }
  }

  __syncthreads();
  short* ob = (short*)smp;
#pragma unroll
  for (int mi = 0; mi < MPW; mi++) {
    int o = m0 + mi * 16 + kg * 4;
#pragma unroll
    for (int nt = 0; nt < 8; nt++) {
      int p = nt * 16 + n;
#pragma unroll
      for (int r = 0; r < 4; r++) {
        float v = fmaxf(acc[mi][nt][r] + bias[o + r], 0.f);
        ob[(o + r) * OP + p] = (short)f2bf_bits(v);
      }
    }
  }
  __syncthreads();
  const unsigned* obu = (const unsigned*)smp;
  for (int idx = t; idx < O * 64; idx += 256) {
    int o = idx >> 6, q = idx & 63;
    long l = base + 2 * q;
    if (l < LT)
      *(unsigned*)(out + (long)o * LT + l) = obu[o * (OP / 2) + q];
  }
}

// 256-thread scan over NN with fused dinv (1 block)
static __device__ void dev_scan(
    char* smp, int t, const int* __restrict__ deg, int* __restrict__ offs,
    float* __restrict__ dinv) {
  int* sums = (int*)smp;
  const int CH = 79;  // 256*79 = 20224 >= NN
  int base = t * CH;
  int s = 0;
  for (int i = 0; i < CH; i++) {
    int idx = base + i;
    if (idx < NN) s += deg[idx] + 1;
  }
  sums[t] = s;
  __syncthreads();
  for (int off = 1; off < 256; off <<= 1) {
    int v = (t >= off) ? sums[t - off] : 0;
    __syncthreads();
    sums[t] += v;
    __syncthreads();
  }
  int run = (t > 0) ? sums[t - 1] : 0;
  for (int i = 0; i < CH; i++) {
    int idx = base + i;
    if (idx < NN) {
      int d = deg[idx];
      offs[idx] = run;
      dinv[idx] = rsqrtf((float)(d + 1));
      run += d + 1;
    }
  }
  if (t == 255) offs[NN] = sums[255];
}

static __device__ void dev_fill(
    int b, int t, const int* __restrict__ src, const int* __restrict__ dst,
    const int* __restrict__ offs, int* __restrict__ cursor, int* __restrict__ csr) {
  int e = b * 256 + t;
  if (e < EE) {
    int d = dst[e];
    int pos = atomicAdd(&cursor[d], 1);
    csr[offs[d] + pos] = src[e];
  } else if (e < EE + NN) {
    int i = e - EE;
    int pos = atomicAdd(&cursor[i], 1);
    csr[offs[i] + pos] = i;
  }
}

// h1: LDS-tiled skinny GEMM, dinv folded (1250 blocks)
static __device__ void dev_h1(
    char* smp, int b, int t, const float* __restrict__ x,
    const float* __restrict__ W1, const float* __restrict__ dinv,
    float* __restrict__ h1s) {
  float* ws = (float*)smp;             // 8192 B
  float* xs = (float*)(smp + 8192);    // 16*132*4 = 8448 B
  int i0 = b * 16;
  for (int i = t; i < 512; i += 256)
    *(float4*)&ws[4 * i] = *(const float4*)&W1[4 * i];
  for (int i = t; i < 512; i += 256) {
    int nl = i >> 5, q = i & 31;
    *(float4*)&xs[nl * 132 + 4 * q] = *(const float4*)&x[(long)(i0 + nl) * FIN + 4 * q];
  }
  __syncthreads();
  int nl = t >> 4, f = t & 15;
  float acc = 0.f;
#pragma unroll 8
  for (int k = 0; k < FIN; k++) acc += xs[nl * 132 + k] * ws[k * 16 + f];
  int n = i0 + nl;
  h1s[n * F1 + f] = acc * dinv[n];
}

// fw1->bf16 + fw2 transpose (1344 blocks)
static __device__ void dev_fwprep(
    int b, int t, const float* __restrict__ fw1, __hip_bfloat16* __restrict__ w1b,
    const float* __restrict__ fw2, float* __restrict__ fw2t) {
  if (b < 1280) {
    int i = b * 256 + t;
    w1b[i] = __float2bfloat16(fw1[i]);
  } else {
    int i = (b - 1280) * 256 + t;  // < 16384
    int o = i / 256, j = i % 256;
    fw2t[j * 64 + o] = fw2[i];
  }
}

// fc1 (m97-style LDS GEMM), 314 blocks
static __device__ void dev_fc1(
    char* smp, int bid, int t, const __hip_bfloat16* __restrict__ t3,
    const __hip_bfloat16* __restrict__ w, const float* __restrict__ fb1,
    float* __restrict__ out) {
  short* As = (short*)smp;             // [2][4096] shorts = 16 KB
  short* Bs = (short*)(smp + 16384);   // [2][4096] shorts = 16 KB
  int wid = t >> 6, lane = t & 63;
  int bn = bid & 1, bm = bid >> 1;
  int mrow = lane & 15, kg = lane >> 4;

  const char* tb = (const char*)t3;
  const char* wb = (const char*)w;
  int u0 = wid * 128 + lane;
  int u1 = u0 + 64;
  int ra0 = u0 >> 2, ca0 = u0 & 3;
  int ra1 = u1 >> 2, ca1 = u1 & 3;
  long ga0 = ((long)min(bm * 128 + ra0, NN - 1) * 1280 + ca0 * 8) * 2;
  long ga1 = ((long)min(bm * 128 + ra1, NN - 1) * 1280 + ca1 * 8) * 2;
  long gb0 = ((long)(bn * 128 + ra0) * 1280 + ca0 * 8) * 2;
  long gb1 = ((long)(bn * 128 + ra1) * 1280 + ca1 * 8) * 2;
  int l0 = (wid * 2 + 0) * 512;
  int l1 = (wid * 2 + 1) * 512;

  auto stage = [&](int buf, int k0) {
    long kb = (long)k0 * 2;
    gl16(tb + ga0 + kb, As + buf * 4096 + l0);
    gl16(tb + ga1 + kb, As + buf * 4096 + l1);
    gl16(wb + gb0 + kb, Bs + buf * 4096 + l0);
    gl16(wb + gb1 + kb, Bs + buf * 4096 + l1);
  };

  stage(0, 0);
  __syncthreads();

  int wr = wid >> 1, wc = wid & 1;
  f32x4 acc[4][4] = {};
  for (int s = 0; s < 40; s++) {
    int buf = s & 1;
    if (s + 1 < 40) stage(buf ^ 1, (s + 1) * 32);
    s16x8 a[4], bb[4];
#pragma unroll
    for (int mi = 0; mi < 4; mi++)
      a[mi] = *(const s16x8*)&As[buf * 4096 + (wr * 64 + mi * 16 + mrow) * 32 + kg * 8];
#pragma unroll
    for (int ni = 0; ni < 4; ni++)
      bb[ni] = *(const s16x8*)&Bs[buf * 4096 + (wc * 64 + ni * 16 + mrow) * 32 + kg * 8];
#pragma unroll
    for (int mi = 0; mi < 4; mi++)
#pragma unroll
      for (int ni = 0; ni < 4; ni++)
        acc[mi][ni] = __builtin_amdgcn_mfma_f32_16x16x32_bf16(a[mi], bb[ni], acc[mi][ni], 0, 0, 0);
    __syncthreads();
  }

  int node_base = bm * 128 + wr * 64 + kg * 4;
  int col_base = bn * 128 + wc * 64 + mrow;
#pragma unroll
  for (int ni = 0; ni < 4; ni++) {
    int col = col_base + ni * 16;
    float bias = fb1[col];
#pragma unroll
    for (int mi = 0; mi < 4; mi++) {
      int node = node_base + mi * 16;
#pragma unroll
      for (int r = 0; r < 4; r++) {
        if (node + r < NN)
          out[(long)(node + r) * 256 + col] = fmaxf(acc[mi][ni][r] + bias, 0.f);
      }
    }
  }
}

// gcn: pre-scaled h1s, 4 waves/block (5000 blocks)
static __device__ void dev_gcn(
    int b, int t, const float* __restrict__ h1s, const int* __restrict__ offs,
    const int* __restrict__ csr, const float* __restrict__ dinv,
    const float* __restrict__ b1, float* __restrict__ g) {
  int wave = t >> 6;
  int lane = t & 63;
  int i = b * 4 + wave;
  int f = lane & 15, grp = lane >> 4;
  int beg = offs[i], end = offs[i + 1];
  float acc = 0.f;
  for (int idx = beg + grp; idx < end; idx += 4)
    acc += h1s[csr[idx] * F1 + f];
  acc += __shfl_down(acc, 32);
  acc += __shfl_down(acc, 16);
  if (lane < 16) g[i * F1 + f] = fmaxf(acc * dinv[i] + b1[f], 0.f);
}

// fc2 v2: block = 16 nodes (LDS 16640B). wave = 4 nodes x 64 outputs.
static __device__ void dev_fc2(
    char* smp, int b, int t, const float* __restrict__ fc1o,
    const float* __restrict__ fw2t, const float* __restrict__ fb2,
    float* __restrict__ out) {
  float* sh = (float*)smp;  // 16*260 floats = 16640 B
  int m0 = b * 16;
  for (int i = t; i < 1024; i += 256) {
    int nd = i >> 6, q = i & 63;
    *(float4*)&sh[nd * 260 + 4 * q] = *(const float4*)&fc1o[(long)(m0 + nd) * 256 + 4 * q];
  }
  __syncthreads();
  int wave = t >> 6, o = t & 63;
  int nb = wave * 4;
  float acc[4];
  float bias = fb2[o];
#pragma unroll
  for (int i = 0; i < 4; i++) acc[i] = bias;
  for (int j = 0; j < 256; j++) {
    float wv = fw2t[j * 64 + o];
#pragma unroll
    for (int i = 0; i < 4; i++) acc[i] += sh[(nb + i) * 260 + j] * wv;
  }
#pragma unroll
  for (int i = 0; i < 4; i++)
    out[(long)(m0 + nb + i) * OUTF + F2 + o] = acc[i];
}

// h2att: block = 32 nodes (625 blocks)
static __device__ void dev_h2att(
    char* smp, int b, int t, const float* __restrict__ g,
    const float* __restrict__ W2, const float* __restrict__ WS,
    const float* __restrict__ WD, unsigned* __restrict__ h2hm,
    float* __restrict__ AS, float* __restrict__ AD) {
  float* glb = (float*)smp;  // 32*20 floats
  int i0 = b * 32;
  for (int idx = t; idx < 512; idx += 256)
    glb[(idx >> 4) * 20 + (idx & 15)] = g[i0 * 16 + idx];
  __syncthreads();

  int f0 = 2 * t;
  int h = t >> 5, c32 = t & 31;
  float w0[16], w1[16];
#pragma unroll
  for (int k = 0; k < 16; k++) {
    float2 wv = *(const float2*)&W2[k * F2 + f0];
    w0[k] = wv.x; w1[k] = wv.y;
  }
  for (int nl = 0; nl < 32; nl++) {
    float a0 = 0.f, a1 = 0.f;
#pragma unroll
    for (int kk = 0; kk < 4; kk++) {
      f32x4 gv = *(const f32x4*)&glb[nl * 20 + 4 * kk];
#pragma unroll
      for (int r = 0; r < 4; r++) {
        a0 += gv[r] * w0[4 * kk + r];
        a1 += gv[r] * w1[4 * kk + r];
      }
    }
    h2hm[((long)h * NN + i0 + nl) * 32 + c32] = f2bf_bits(a0) | (f2bf_bits(a1) << 16);
  }
  int nl = t >> 3, hh = t & 7;
  float s = 0.f, d = 0.f;
#pragma unroll
  for (int k = 0; k < 16; k++) {
    float gv = glb[nl * 20 + k];
    s += gv * WS[k * 8 + hh];
    d += gv * WD[k * 8 + hh];
  }
  AS[(long)hh * NN + i0 + nl] = s;
  AD[(long)hh * NN + i0 + nl] = d;
}

// ================= fused launches =================

// L1: prep (124) + zero CURSOR..DEG (157) = 281 blocks
__global__ __launch_bounds__(256) void k_prep(
    const float* cw1, float* wt1, const float* cw2, short* wb2,
    const float* cw3, short* wb3, const float* W2, const float* asrc,
    const float* adst, float* WS, float* WD, int* zbase) {
  int b = blockIdx.x, t = threadIdx.x;
  if (b < 124) dev_prep_all(b, t, cw1, wt1, cw2, wb2, cw3, wb3, W2, asrc, adst, WS, WD);
  else {
    int i = (b - 124) * 256 + t;
    if (i < 40000) zbase[i] = 0;
  }
}

// L2: conv1 (3125) + deg (2500) = 5625 blocks, 6400 B dyn LDS
__global__ __launch_bounds__(256) void k_conv1_deg(
    const float* temporal, __hip_bfloat16* T1b, const float* wt1, const float* cb1,
    const int* e_dst, int* deg) {
  extern __shared__ char smem[];
  int b = blockIdx.x;
  if (b < 3125) dev_conv_fast(smem, b, threadIdx.x, temporal, T1b, wt1, cb1);
  else {
    int e = (b - 3125) * 256 + threadIdx.x;
    if (e < EE) atomicAdd(&deg[e_dst[e]], 1);
  }
}

// L3: conv2 (1563) + scan (1) + fwprep (1344) = 2908 blocks, 16896 B dyn LDS
__global__ __launch_bounds__(256) void k_conv2_scan(
    const short* T1b, short* T2b, const short* wb2, const float* cb2,
    const int* deg, int* offs, float* dinv,
    const float* fw1, __hip_bfloat16* w1b, const float* fw2, float* fw2t) {
  extern __shared__ char smem[];
  int b = blockIdx.x;
  if (b < 1563) dev_conv_mfma<32, 64, 1>(smem, b, threadIdx.x, T1b, T2b, wb2, cb2);
  else if (b == 1563) dev_scan(smem, threadIdx.x, deg, offs, dinv);
  else dev_fwprep(b - 1564, threadIdx.x, fw1, w1b, fw2, fw2t);
}

// L4: conv3 (1563) + fill (2579) + h1 (1250) = 5392 blocks, 33792 B dyn LDS
__global__ __launch_bounds__(256) void k_conv3_misc(
    const short* T2b, short* T3b, const short* wb3, const float* cb3,
    const int* e_src, const int* e_dst, const int* offs, int* cursor, int* csr,
    const float* x, const float* W1, const float* dinv, float* h1s) {
  extern __shared__ char smem[];
  int b = blockIdx.x, t = threadIdx.x;
  if (b < 1563) dev_conv_mfma<64, 128, 2>(smem, b, t, T2b, T3b, wb3, cb3);
  else if (b < 4142) dev_fill(b - 1563, t, e_src, e_dst, offs, cursor, csr);
  else dev_h1(smem, b - 4142, t, x, W1, dinv, h1s);
}

// L5: fc1 (314) + gcn (5000) = 5314 blocks, 32768 B dyn LDS
__global__ __launch_bounds__(256) void k_fc1_gcn(
    const __hip_bfloat16* t3, const __hip_bfloat16* w, const float* fb1, float* fc1o,
    const float* h1s, const int* offs, const int* csr, const float* dinv,
    const float* b1, float* g) {
  extern __shared__ char smem[];
  int b = blockIdx.x, t = threadIdx.x;
  if (b < 314) dev_fc1(smem, b, t, t3, w, fb1, fc1o);
  else dev_gcn(b - 314, t, h1s, offs, csr, dinv, b1, g);
}

// L6: fc2 (1250) + h2att (625) = 1875 blocks, 16640 B dyn LDS
__global__ __launch_bounds__(256) void k_fc2_h2att(
    const float* fc1o, const float* fw2t, const float* fb2, float* out,
    const float* g, const float* W2, const float* WS, const float* WD,
    unsigned* h2hm, float* AS, float* AD) {
  extern __shared__ char smem[];
  int b = blockIdx.x, t = threadIdx.x;
  if (b < 1250) dev_fc2(smem, b, t, fc1o, fw2t, fb2, out);
  else dev_h2att(smem, b - 1250, t, g, W2, WS, WD, h2hm, AS, AD);
}

// L7: gat v3 (known-good 68us): one wave per (dst node, head).
__global__ __launch_bounds__(256) void gat_fused_kernel(
    const unsigned* __restrict__ h2hm, const float* __restrict__ AS,
    const float* __restrict__ AD, const int* __restrict__ offs,
    const int* __restrict__ csr, const float* __restrict__ b2,
    float* __restrict__ out) {
  __shared__ __align__(16) unsigned long long pairs[4][64];
  __shared__ __align__(16) float accb[4][8][68];
  int h = blockIdx.x & 7;
  int gn = blockIdx.x >> 3;
  int wave = threadIdx.x >> 6;
  int lane = threadIdx.x & 63;
  int i = gn * 4 + wave;
  int beg = offs[i], end = offs[i + 1];
  const float* ASh = AS + (long)h * NN;
  float ad = AD[(long)h * NN + i];
  const char* hb2 = (const char*)(h2hm + (long)h * NN * 32);
  int octet = lane >> 3, q = lane & 7;
  unsigned laneoff = (unsigned)q * 16u;
  unsigned long long* prs = &pairs[wave][0];

  float acc[8] = {0.f, 0.f, 0.f, 0.f, 0.f, 0.f, 0.f, 0.f};
  float sum = 0.f;

  for (int c = beg; c < end; c += 64) {
    int cnt = end - c;
    if (cnt > 64) cnt = 64;
    unsigned off = 0u;
    float ex = 0.f;
    if (lane < cnt) {
      int s = csr[c + lane];
      float e = ASh[s] + ad;
      e = (e >= 0.f) ? e : 0.2f * e;
      ex = __expf(e);
      sum += ex;
      off = (unsigned)s << 7;  // s * 128 bytes
    }
    asm volatile("" ::: "memory");
    prs[lane] = ((unsigned long long)__float_as_uint(ex) << 32) | off;
    asm volatile("" ::: "memory");
    int nj = (cnt + 7) >> 3;
    const unsigned long long* pp = prs + octet;
#pragma unroll 2
    for (int j = 0; j < nj; j++) {
      unsigned long long pr = pp[(long)j * 8];
      unsigned voff = (unsigned)pr | laneoff;
      float aj = __uint_as_float((unsigned)(pr >> 32));
      uint4 v = *(const uint4*)(hb2 + voff);
      acc[0] += __uint_as_float(v.x << 16) * aj;
      acc[1] += __uint_as_float(v.x & 0xffff0000u) * aj;
      acc[2] += __uint_as_float(v.y << 16) * aj;
      acc[3] += __uint_as_float(v.y & 0xffff0000u) * aj;
      acc[4] += __uint_as_float(v.z << 16) * aj;
      acc[5] += __uint_as_float(v.z & 0xffff0000u) * aj;
      acc[6] += __uint_as_float(v.w << 16) * aj;
      acc[7] += __uint_as_float(v.w & 0xffff0000u) * aj;
    }
    asm volatile("" ::: "memory");
  }
#pragma unroll
  for (int o = 32; o > 0; o >>= 1) sum += __shfl_xor(sum, o, 64);
  float rinv = 1.f / (sum + 1e-16f);
  float* ab = &accb[wave][octet][q * 8];
  f32x4 lo = {acc[0], acc[1], acc[2], acc[3]};
  f32x4 hi = {acc[4], acc[5], acc[6], acc[7]};
  *(f32x4*)ab = lo;
  *(f32x4*)(ab + 4) = hi;
  asm volatile("" ::: "memory");
  float r = 0.f;
#pragma unroll
  for (int o = 0; o < 8; o++) r += accb[wave][o][lane];
  out[(long)i * OUTF + h * 64 + lane] = r * rinv + b2[h * 64 + lane];
}

// ---------------- launcher ----------------

extern "C" void kernel_launch(void* const* d_in, const int* in_sizes, int n_in,
                              void* d_out, int out_size, void* d_ws, size_t ws_size,
                              hipStream_t stream) {
  const float* x        = (const float*)d_in[0];
  const int*   eidx     = (const int*)d_in[1];
  const float* temporal = (const float*)d_in[2];
  const float* W1       = (const float*)d_in[3];
  const float* b1       = (const float*)d_in[4];
  const float* W2       = (const float*)d_in[5];
  const float* att_src  = (const float*)d_in[6];
  const float* att_dst  = (const float*)d_in[7];
  const float* b2       = (const float*)d_in[8];
  const float* cw1      = (const float*)d_in[9];
  const float* cb1      = (const float*)d_in[10];
  const float* cw2      = (const float*)d_in[11];
  const float* cb2      = (const float*)d_in[12];
  const float* cw3      = (const float*)d_in[13];
  const float* cb3      = (const float*)d_in[14];
  const float* fw1      = (const float*)d_in[15];
  const float* fb1      = (const float*)d_in[16];
  const float* fw2      = (const float*)d_in[17];
  const float* fb2      = (const float*)d_in[18];
  float* out = (float*)d_out;

  const int* e_src = eidx;
  const int* e_dst = eidx + EE;

  char* ws = (char*)d_ws;
  // ---- workspace layout with lifetime-disjoint aliasing (launch index L1..L7) ----
  int*   CURSOR = (int*)  (ws + 0);          // [L1 zero, L4 fill]      80,000
  int*   DEG    = (int*)  (ws + 80000);      // [L1 zero, L2 W, L3 R]   -> 160,000
  int*   OFFS   = (int*)  (ws + 160000);     // [L3 W, L4/L5/L7 R]      -> 240,128
  float* DINV   = (float*)(ws + 240128);     // [L3 W, L4/L5 R]         -> 320,128
  int*   CSR    = (int*)  (ws + 320128);     // [L4 W, L5/L7 R]         -> 2,960,128
  float* H1S    = (float*)(ws + 2960128);    // [L4 W, L5 R]            -> 4,240,128
  float* G      = (float*)(ws + 4240128);    // [L5 W, L6 R]            -> 5,520,128
  float* AS     = (float*)(ws + 5520128);    // [L6 W, L7 R]            -> 6,160,128
  float* AD     = (float*)(ws + 6160128);    // [L6 W, L7 R]            -> 6,800,128
  // big buffers, time-disjoint aliases:
  __hip_bfloat16* T2b = (__hip_bfloat16*)(ws + 6800128);   // [L3 W, L4 R] 25.6M -> 32,400,128
  float* FC1OUT = (float*)(ws + 6800128);                  // [L5 W, L6 R] 20.48M (T2b dead)
  __hip_bfloat16* T1b = (__hip_bfloat16*)(ws + 32400128);  // [L2 W, L3 R] 12.8M -> 45,200,128
  unsigned* H2HM = (unsigned*)(ws + 32400128);             // [L6 W, L7 R] 20.48M (T3b dead)
  __hip_bfloat16* T3b = (__hip_bfloat16*)(ws + 32400128);  // [L4 W, L5 R] 51.2M -> 83,600,128 (T1b dead)
  __hip_bfloat16* FW1BF = (__hip_bfloat16*)(ws + 83600128);// [L3 W, L5 R] -> 84,255,488
  float* FW2T = (float*)(ws + 84255488);                   // [L3 W, L6 R] -> 84,321,024
  // conv weight + att-fold scratch in d_out (consumed before overwritten):
  float* WT1 = out;                              // [L1 W, L2 R] bytes 0..3,072
  short* WB2 = (short*)((char*)d_out + 3072);    // [L1 W, L3 R] -> 15,360
  short* WB3 = (short*)((char*)d_out + 15360);   // [L1 W, L4 R] -> 64,512
  float* WSM = (float*)((char*)d_out + 64512);   // [L1 W, L6 R] -> 65,024
  float* WDM = (float*)((char*)d_out + 65024);   // -> 65,536

  // L1: prep + zero(CURSOR,DEG = 40000 ints)
  k_prep<<<281, 256, 0, stream>>>(cw1, WT1, cw2, WB2, cw3, WB3,
                                  W2, att_src, att_dst, WSM, WDM, (int*)ws);
  // L2: conv1 || deg
  k_conv1_deg<<<5625, 256, 6400, stream>>>(temporal, T1b, WT1, cb1, e_dst, DEG);
  // L3: conv2 || scan(+dinv) || fwprep
  k_conv2_scan<<<2908, 256, 16896, stream>>>((const short*)T1b, (short*)T2b, WB2, cb2,
                                             DEG, OFFS, DINV,
                                             fw1, FW1BF, fw2, FW2T);
  // L4: conv3 || fill || h1
  k_conv3_misc<<<5392, 256, 33792, stream>>>((const short*)T2b, (short*)T3b, WB3, cb3,
                                             e_src, e_dst, OFFS, CURSOR, CSR,
                                             x, W1, DINV, H1S);
  // L5: fc1 || gcn
  k_fc1_gcn<<<5314, 256, 32768, stream>>>(T3b, FW1BF, fb1, FC1OUT,
                                          H1S, OFFS, CSR, DINV, b1, G);
  // L6: fc2 || h2att
  k_fc2_h2att<<<1875, 256, 16640, stream>>>(FC1OUT, FW2T, fb2, out,
                                            G, W2, WSM, WDM, H2HM, AS, AD);
  // L7: gat
  gat_fused_kernel<<<(NN / 4) * 8, 256, 0, stream>>>(H2HM, AS, AD, OFFS, CSR, b2, out);
}